// Round 1
// baseline (6184.725 us; speedup 1.0000x reference)
//
#include <hip/hip_runtime.h>
#include <stdint.h>

#define T_STEPS 256
#define BATCH 64
#define DIM 1024
#define HID 1024
#define RANK 256
#define FOURH 4096
#define M1 (T_STEPS * BATCH) // 16384

typedef __bf16 bf16_t;
typedef bf16_t bf16x8 __attribute__((ext_vector_type(8)));
typedef float f32x4 __attribute__((ext_vector_type(4)));

union frag_cast { uint4 u; bf16x8 v; };

__device__ __forceinline__ bf16x8 load_frag(const unsigned short* p) {
  frag_cast c; c.u = *reinterpret_cast<const uint4*>(p); return c.v;
}
__device__ __forceinline__ unsigned short f2bf(float f) {
  union { float f; uint32_t u; } v; v.f = f;
  uint32_t u = v.u;
  return (unsigned short)((u + 0x7fffu + ((u >> 16) & 1u)) >> 16);
}
__device__ __forceinline__ float bf2f(unsigned short h) {
  union { uint32_t u; float f; } v; v.u = ((uint32_t)h) << 16; return v.f;
}

// Pack a [K x N] logical B matrix (f32 source) into MFMA B-fragment layout:
// frag (kc, nt): lane l slot s holds B[kc*32 + (l>>4)*8 + s][nt*16 + (l&15)].
// transposed=1: B[k][n] = src[n*ld + k]  (contiguous 8-elem reads)
// transposed=0: B[k][n] = src[k*ld + n]
__global__ void k_pack(const float* __restrict__ src, unsigned short* __restrict__ dst,
                       int NT, int ld, int transposed) {
  int id = blockIdx.x * blockDim.x + threadIdx.x;
  int lane = id & 63;
  int fi = id >> 6; // kc*NT + nt
  int nt = fi % NT, kc = fi / NT;
  int k0 = kc * 32 + ((lane >> 4) * 8);
  int n  = nt * 16 + (lane & 15);
  unsigned short vals[8];
  if (transposed) {
    const float* p = src + (size_t)n * ld + k0;
#pragma unroll
    for (int s = 0; s < 8; ++s) vals[s] = f2bf(p[s]);
  } else {
#pragma unroll
    for (int s = 0; s < 8; ++s) vals[s] = f2bf(src[(size_t)(k0 + s) * ld + n]);
  }
  union { unsigned short u16[8]; uint4 u; } o;
#pragma unroll
  for (int s = 0; s < 8; ++s) o.u16[s] = vals[s];
  *reinterpret_cast<uint4*>(dst + (size_t)id * 8) = o.u;
}

// corr_x[j] = dia_x[j%H] - dot(u_x[j%H,:], w_x[j,:]);  bias[j] = b_x[j]+b_h[j]
__global__ void k_coef(const float* __restrict__ u_x, const float* __restrict__ w_x,
                       const float* __restrict__ dia_x,
                       const float* __restrict__ b_x, const float* __restrict__ b_h,
                       float* __restrict__ corr, float* __restrict__ bias) {
  int wv = threadIdx.x >> 6, lane = threadIdx.x & 63;
  int j = blockIdx.x * 4 + wv;
  int e = j & (HID - 1);
  const float* up = u_x + (size_t)e * RANK + lane * 4;
  const float* wp = w_x + (size_t)j * RANK + lane * 4;
  float s = up[0] * wp[0] + up[1] * wp[1] + up[2] * wp[2] + up[3] * wp[3];
#pragma unroll
  for (int off = 32; off > 0; off >>= 1) s += __shfl_xor(s, off, 64);
  if (lane == 0) {
    corr[j] = dia_x[e] - s;
    bias[j] = b_x[j] + b_h[j];
  }
}

__global__ void k_init(const float* __restrict__ h0, unsigned short* __restrict__ hbuf,
                       unsigned int* __restrict__ ctr) {
  int i = blockIdx.x * blockDim.x + threadIdx.x;
  if (i == 0) *ctr = 0u;
  hbuf[i] = f2bf(h0[i]); // exactly BATCH*HID threads
}

// C[M x 64*gridDim.x] = A_f32[M x 32*KC] @ packB, store bf16.
// dia != null: C is AhT [j][d]; override C[j][d] = dia[d] when d == j % HID.
__global__ void k_gemm_a32(const float* __restrict__ A, int lda,
                           const unsigned short* __restrict__ packB, int NTtot,
                           int KC, unsigned short* __restrict__ C, int ldc,
                           const float* __restrict__ dia) {
  int w = threadIdx.x >> 6, lane = threadIdx.x & 63;
  int q = lane >> 4, ln = lane & 15;
  int m0 = blockIdx.y * 64, n0 = blockIdx.x * 64;
  int arow = m0 + w * 16 + ln;
  f32x4 acc[4] = {};
  for (int kc = 0; kc < KC; ++kc) {
    const float* ap = A + (size_t)arow * lda + kc * 32 + q * 8;
    float4 x0 = *reinterpret_cast<const float4*>(ap);
    float4 x1 = *reinterpret_cast<const float4*>(ap + 4);
    bf16x8 a;
    a[0] = (bf16_t)x0.x; a[1] = (bf16_t)x0.y; a[2] = (bf16_t)x0.z; a[3] = (bf16_t)x0.w;
    a[4] = (bf16_t)x1.x; a[5] = (bf16_t)x1.y; a[6] = (bf16_t)x1.z; a[7] = (bf16_t)x1.w;
#pragma unroll
    for (int nt = 0; nt < 4; ++nt) {
      bf16x8 b = load_frag(packB + ((size_t)(kc * NTtot + blockIdx.x * 4 + nt) * 64 + lane) * 8);
      acc[nt] = __builtin_amdgcn_mfma_f32_16x16x32_bf16(a, b, acc[nt], 0, 0, 0);
    }
  }
#pragma unroll
  for (int nt = 0; nt < 4; ++nt) {
    int ccol = n0 + nt * 16 + ln;
#pragma unroll
    for (int r = 0; r < 4; ++r) {
      int crow = m0 + w * 16 + q * 4 + r;
      float v = acc[nt][r];
      if (dia != nullptr && ccol == (crow & (HID - 1))) v = dia[ccol];
      C[(size_t)crow * ldc + ccol] = f2bf(v);
    }
  }
}

// Repack AhT [j][d] (bf16) into per-(cg,gate,kc) B-fragment layout for k_rec.
__global__ void k_packAh(const unsigned short* __restrict__ AhT, unsigned short* __restrict__ dst) {
  int id = blockIdx.x * blockDim.x + threadIdx.x;
  int lane = id & 63;
  int fi = id >> 6;        // (cg*4+g)*32 + kc
  int kc = fi & 31;
  int g  = (fi >> 5) & 3;
  int cg = fi >> 7;
  int j  = g * HID + cg * 16 + (lane & 15);
  int d0 = kc * 32 + ((lane >> 4) * 8);
  uint4 v = *reinterpret_cast<const uint4*>(AhT + (size_t)j * HID + d0);
  *reinterpret_cast<uint4*>(dst + (size_t)id * 8) = v;
}

// gx[m][j] = P[m,:] @ w_xT[:,j] + x[m][j%H]*corr[j] + bias[j], store bf16.
__global__ void k_gemm2(const unsigned short* __restrict__ P,
                        const unsigned short* __restrict__ packWx,
                        const float* __restrict__ x,
                        const float* __restrict__ corr, const float* __restrict__ bias,
                        unsigned short* __restrict__ gx) {
  int w = threadIdx.x >> 6, lane = threadIdx.x & 63;
  int q = lane >> 4, ln = lane & 15;
  int m0 = blockIdx.y * 64, n0 = blockIdx.x * 64;
  int arow = m0 + w * 16 + ln;
  f32x4 acc[4] = {};
#pragma unroll
  for (int kc = 0; kc < 8; ++kc) {
    bf16x8 a = load_frag(P + (size_t)arow * RANK + kc * 32 + q * 8);
#pragma unroll
    for (int nt = 0; nt < 4; ++nt) {
      bf16x8 b = load_frag(packWx + ((size_t)(kc * 256 + blockIdx.x * 4 + nt) * 64 + lane) * 8);
      acc[nt] = __builtin_amdgcn_mfma_f32_16x16x32_bf16(a, b, acc[nt], 0, 0, 0);
    }
  }
#pragma unroll
  for (int nt = 0; nt < 4; ++nt) {
    int j = n0 + nt * 16 + ln;
    int e = j & (HID - 1);
    float cj = corr[j], bj = bias[j];
#pragma unroll
    for (int r = 0; r < 4; ++r) {
      int m = m0 + w * 16 + q * 4 + r;
      float v = acc[nt][r] + x[(size_t)m * DIM + e] * cj + bj;
      gx[(size_t)m * FOURH + j] = f2bf(v);
    }
  }
}

// Persistent recurrent kernel: 256 blocks (1/CU), one grid barrier per step.
// block = (bg = blk>>6) batch-group of 16 rows x (cg = blk&63) 16 e-columns.
// Wave w = gate w; B-fragments of A_h register-resident for all 256 steps.
__global__ __launch_bounds__(256, 1) void k_rec(
    const unsigned short* __restrict__ pAh,
    const unsigned short* __restrict__ gx,
    const float* __restrict__ c0,
    unsigned short* __restrict__ hbuf,
    float* __restrict__ out,
    unsigned int* __restrict__ ctr) {
  const int tid = threadIdx.x;
  const int w = tid >> 6, lane = tid & 63;
  const int q = lane >> 4, ln = lane & 15;
  const int blk = blockIdx.x;
  const int cg = blk & 63, bg = blk >> 6;

  bf16x8 bfr[32];
#pragma unroll
  for (int kc = 0; kc < 32; ++kc)
    bfr[kc] = load_frag(pAh + ((size_t)((cg * 4 + w) * 32 + kc) * 64 + lane) * 8);

  const int rb = tid >> 4, ee = tid & 15;
  const int brow = bg * 16 + rb;
  const int e = cg * 16 + ee;
  float c = c0[brow * HID + e];

  __shared__ float pre[4][16][16];

  const int arow = bg * 16 + ln;

  for (int t = 0; t < T_STEPS; ++t) {
    const int cur = t & 1;
    const unsigned short* hrow = hbuf + cur * (BATCH * HID) + arow * HID + q * 8;
    f32x4 acc0 = {}; f32x4 acc1 = {};
#pragma unroll
    for (int kc = 0; kc < 32; kc += 2) {
      bf16x8 a0 = load_frag(hrow + kc * 32);
      bf16x8 a1 = load_frag(hrow + kc * 32 + 32);
      acc0 = __builtin_amdgcn_mfma_f32_16x16x32_bf16(a0, bfr[kc], acc0, 0, 0, 0);
      acc1 = __builtin_amdgcn_mfma_f32_16x16x32_bf16(a1, bfr[kc + 1], acc1, 0, 0, 0);
    }
#pragma unroll
    for (int r = 0; r < 4; ++r) pre[w][q * 4 + r][ln] = acc0[r] + acc1[r];
    __syncthreads();

    const size_t grow = ((size_t)t * BATCH + brow) * FOURH;
    float p0 = pre[0][rb][ee] + bf2f(gx[grow + e]);
    float p1 = pre[1][rb][ee] + bf2f(gx[grow + HID + e]);
    float p2 = pre[2][rb][ee] + bf2f(gx[grow + 2 * HID + e]);
    float p3 = pre[3][rb][ee] + bf2f(gx[grow + 3 * HID + e]);
    float gi = 1.f / (1.f + __expf(-p0));
    float gf = 1.f / (1.f + __expf(-p1));
    float go = 1.f / (1.f + __expf(-p2));
    float gn = tanhf(p3);
    c = gf * c + gi * gn;
    float hn = go * tanhf(c);
    out[((size_t)t * BATCH + brow) * HID + e] = hn;
    hbuf[(cur ^ 1) * (BATCH * HID) + brow * HID + e] = f2bf(hn);
    if (t == T_STEPS - 1) {
      out[(size_t)T_STEPS * BATCH * HID + brow * HID + e] = hn;           // h_f
      out[(size_t)T_STEPS * BATCH * HID + BATCH * HID + brow * HID + e] = c; // c_f
    }
    __syncthreads();
    if (tid == 0) {
      __threadfence();
      atomicAdd(ctr, 1u);
      const unsigned int target = (unsigned int)(t + 1) * 256u;
      while (__hip_atomic_load(ctr, __ATOMIC_RELAXED, __HIP_MEMORY_SCOPE_AGENT) < target)
        __builtin_amdgcn_s_sleep(2);
      __threadfence();
    }
    __syncthreads();
  }
}

extern "C" void kernel_launch(void* const* d_in, const int* in_sizes, int n_in,
                              void* d_out, int out_size, void* d_ws, size_t ws_size,
                              hipStream_t stream) {
  const float* x     = (const float*)d_in[0];
  const float* h0    = (const float*)d_in[1];
  const float* c0    = (const float*)d_in[2];
  const float* u_x   = (const float*)d_in[3];
  const float* u_h   = (const float*)d_in[4];
  const float* w_x   = (const float*)d_in[5];
  const float* w_h   = (const float*)d_in[6];
  const float* b_x   = (const float*)d_in[7];
  const float* b_h   = (const float*)d_in[8];
  const float* dia_x = (const float*)d_in[9];
  const float* dia_h = (const float*)d_in[10];
  float* out = (float*)d_out;
  (void)in_sizes; (void)n_in; (void)out_size; (void)ws_size;

  char* base = (char*)d_ws;
  size_t off = 0;
  auto alloc = [&](size_t bytes) -> void* {
    void* p = base + off;
    off = (off + bytes + 255) & ~(size_t)255;
    return p;
  };
  unsigned short* pUx  = (unsigned short*)alloc((size_t)32 * 16 * 64 * 8 * 2);
  unsigned short* pUhT = (unsigned short*)alloc((size_t)8 * 64 * 64 * 8 * 2);
  unsigned short* pWx  = (unsigned short*)alloc((size_t)8 * 256 * 64 * 8 * 2);
  float* corr = (float*)alloc((size_t)FOURH * 4);
  float* bias = (float*)alloc((size_t)FOURH * 4);
  unsigned short* hbuf = (unsigned short*)alloc((size_t)2 * BATCH * HID * 2);
  unsigned int* ctr    = (unsigned int*)alloc(256);
  unsigned short* P    = (unsigned short*)alloc((size_t)M1 * RANK * 2);
  unsigned short* AhT  = (unsigned short*)alloc((size_t)FOURH * HID * 2);
  unsigned short* pAh  = (unsigned short*)alloc((size_t)64 * 4 * 32 * 64 * 8 * 2);
  unsigned short* gx   = (unsigned short*)alloc((size_t)M1 * FOURH * 2);

  // B-operand packs (one-time, reused by GEMMs / recurrence)
  k_pack<<<128, 256, 0, stream>>>(u_x, pUx, 16, RANK, 0);   // G1 B: u_x [1024 x 256]
  k_pack<<<128, 256, 0, stream>>>(u_h, pUhT, 64, RANK, 1);  // G3 B: u_hT [256 x 1024]
  k_pack<<<512, 256, 0, stream>>>(w_x, pWx, 256, RANK, 1);  // G2 B: w_xT [256 x 4096]
  k_coef<<<1024, 256, 0, stream>>>(u_x, w_x, dia_x, b_x, b_h, corr, bias);
  k_init<<<256, 256, 0, stream>>>(h0, hbuf, ctr);
  // G1: P[16384 x 256] = X @ u_x
  k_gemm_a32<<<dim3(4, 256), 256, 0, stream>>>(x, DIM, pUx, 16, 32, P, RANK, nullptr);
  // G3: AhT[4096 x 1024] = w_h @ u_hT, diagonal overridden with dia_h
  k_gemm_a32<<<dim3(16, 64), 256, 0, stream>>>(w_h, RANK, pUhT, 64, 8, AhT, HID, dia_h);
  k_packAh<<<2048, 256, 0, stream>>>(AhT, pAh);
  // G2: gx = P @ w_xT + x*corr + bias  (bf16)
  k_gemm2<<<dim3(64, 256), 256, 0, stream>>>(P, pWx, x, corr, bias, gx);
  // Persistent recurrence
  k_rec<<<256, 256, 0, stream>>>(pAh, gx, c0, hbuf, out, ctr);
}

// Round 2
// 4807.613 us; speedup vs baseline: 1.2864x; 1.2864x over previous
//
#include <hip/hip_runtime.h>
#include <stdint.h>

#define T_STEPS 256
#define BATCH 64
#define DIM 1024
#define HID 1024
#define RANK 256
#define FOURH 4096
#define M1 (T_STEPS * BATCH) // 16384

typedef __bf16 bf16_t;
typedef bf16_t bf16x8 __attribute__((ext_vector_type(8)));
typedef float f32x4 __attribute__((ext_vector_type(4)));

union frag_cast { uint4 u; bf16x8 v; };

__device__ __forceinline__ bf16x8 load_frag(const unsigned short* p) {
  frag_cast c; c.u = *reinterpret_cast<const uint4*>(p); return c.v;
}
__device__ __forceinline__ unsigned short f2bf(float f) {
  union { float f; uint32_t u; } v; v.f = f;
  uint32_t u = v.u;
  return (unsigned short)((u + 0x7fffu + ((u >> 16) & 1u)) >> 16);
}
__device__ __forceinline__ float bf2f(unsigned short h) {
  union { uint32_t u; float f; } v; v.u = ((uint32_t)h) << 16; return v.f;
}

// Pack a [K x N] logical B matrix (f32 source) into MFMA B-fragment layout:
// frag (kc, nt): lane l slot s holds B[kc*32 + (l>>4)*8 + s][nt*16 + (l&15)].
// transposed=1: B[k][n] = src[n*ld + k]  (contiguous 8-elem reads)
// transposed=0: B[k][n] = src[k*ld + n]
__global__ void k_pack(const float* __restrict__ src, unsigned short* __restrict__ dst,
                       int NT, int ld, int transposed) {
  int id = blockIdx.x * blockDim.x + threadIdx.x;
  int lane = id & 63;
  int fi = id >> 6; // kc*NT + nt
  int nt = fi % NT, kc = fi / NT;
  int k0 = kc * 32 + ((lane >> 4) * 8);
  int n  = nt * 16 + (lane & 15);
  unsigned short vals[8];
  if (transposed) {
    const float* p = src + (size_t)n * ld + k0;
#pragma unroll
    for (int s = 0; s < 8; ++s) vals[s] = f2bf(p[s]);
  } else {
#pragma unroll
    for (int s = 0; s < 8; ++s) vals[s] = f2bf(src[(size_t)(k0 + s) * ld + n]);
  }
  union { unsigned short u16[8]; uint4 u; } o;
#pragma unroll
  for (int s = 0; s < 8; ++s) o.u16[s] = vals[s];
  *reinterpret_cast<uint4*>(dst + (size_t)id * 8) = o.u;
}

// corr_x[j] = dia_x[j%H] - dot(u_x[j%H,:], w_x[j,:]);  bias[j] = b_x[j]+b_h[j]
__global__ void k_coef(const float* __restrict__ u_x, const float* __restrict__ w_x,
                       const float* __restrict__ dia_x,
                       const float* __restrict__ b_x, const float* __restrict__ b_h,
                       float* __restrict__ corr, float* __restrict__ bias) {
  int wv = threadIdx.x >> 6, lane = threadIdx.x & 63;
  int j = blockIdx.x * 4 + wv;
  int e = j & (HID - 1);
  const float* up = u_x + (size_t)e * RANK + lane * 4;
  const float* wp = w_x + (size_t)j * RANK + lane * 4;
  float s = up[0] * wp[0] + up[1] * wp[1] + up[2] * wp[2] + up[3] * wp[3];
#pragma unroll
  for (int off = 32; off > 0; off >>= 1) s += __shfl_xor(s, off, 64);
  if (lane == 0) {
    corr[j] = dia_x[e] - s;
    bias[j] = b_x[j] + b_h[j];
  }
}

__global__ void k_init(const float* __restrict__ h0, unsigned short* __restrict__ hbuf,
                       unsigned int* __restrict__ slots) {
  int i = blockIdx.x * blockDim.x + threadIdx.x;
  if (i < 256 * 16) slots[i] = 0u;  // 256 padded barrier slots (64B each)
  hbuf[i] = f2bf(h0[i]); // exactly BATCH*HID threads
}

// C[M x 64*gridDim.x] = A_f32[M x 32*KC] @ packB, store bf16.
// dia != null: C is AhT [j][d]; override C[j][d] = dia[d] when d == j % HID.
__global__ void k_gemm_a32(const float* __restrict__ A, int lda,
                           const unsigned short* __restrict__ packB, int NTtot,
                           int KC, unsigned short* __restrict__ C, int ldc,
                           const float* __restrict__ dia) {
  int w = threadIdx.x >> 6, lane = threadIdx.x & 63;
  int q = lane >> 4, ln = lane & 15;
  int m0 = blockIdx.y * 64, n0 = blockIdx.x * 64;
  int arow = m0 + w * 16 + ln;
  f32x4 acc[4] = {};
  for (int kc = 0; kc < KC; ++kc) {
    const float* ap = A + (size_t)arow * lda + kc * 32 + q * 8;
    float4 x0 = *reinterpret_cast<const float4*>(ap);
    float4 x1 = *reinterpret_cast<const float4*>(ap + 4);
    bf16x8 a;
    a[0] = (bf16_t)x0.x; a[1] = (bf16_t)x0.y; a[2] = (bf16_t)x0.z; a[3] = (bf16_t)x0.w;
    a[4] = (bf16_t)x1.x; a[5] = (bf16_t)x1.y; a[6] = (bf16_t)x1.z; a[7] = (bf16_t)x1.w;
#pragma unroll
    for (int nt = 0; nt < 4; ++nt) {
      bf16x8 b = load_frag(packB + ((size_t)(kc * NTtot + blockIdx.x * 4 + nt) * 64 + lane) * 8);
      acc[nt] = __builtin_amdgcn_mfma_f32_16x16x32_bf16(a, b, acc[nt], 0, 0, 0);
    }
  }
#pragma unroll
  for (int nt = 0; nt < 4; ++nt) {
    int ccol = n0 + nt * 16 + ln;
#pragma unroll
    for (int r = 0; r < 4; ++r) {
      int crow = m0 + w * 16 + q * 4 + r;
      float v = acc[nt][r];
      if (dia != nullptr && ccol == (crow & (HID - 1))) v = dia[ccol];
      C[(size_t)crow * ldc + ccol] = f2bf(v);
    }
  }
}

// Repack AhT [j][d] (bf16) into per-(cg,gate,kc) B-fragment layout for k_rec.
__global__ void k_packAh(const unsigned short* __restrict__ AhT, unsigned short* __restrict__ dst) {
  int id = blockIdx.x * blockDim.x + threadIdx.x;
  int lane = id & 63;
  int fi = id >> 6;        // (cg*4+g)*32 + kc
  int kc = fi & 31;
  int g  = (fi >> 5) & 3;
  int cg = fi >> 7;
  int j  = g * HID + cg * 16 + (lane & 15);
  int d0 = kc * 32 + ((lane >> 4) * 8);
  uint4 v = *reinterpret_cast<const uint4*>(AhT + (size_t)j * HID + d0);
  *reinterpret_cast<uint4*>(dst + (size_t)id * 8) = v;
}

// gx[m][j] = P[m,:] @ w_xT[:,j] + x[m][j%H]*corr[j] + bias[j], store bf16.
__global__ void k_gemm2(const unsigned short* __restrict__ P,
                        const unsigned short* __restrict__ packWx,
                        const float* __restrict__ x,
                        const float* __restrict__ corr, const float* __restrict__ bias,
                        unsigned short* __restrict__ gx) {
  int w = threadIdx.x >> 6, lane = threadIdx.x & 63;
  int q = lane >> 4, ln = lane & 15;
  int m0 = blockIdx.y * 64, n0 = blockIdx.x * 64;
  int arow = m0 + w * 16 + ln;
  f32x4 acc[4] = {};
#pragma unroll
  for (int kc = 0; kc < 8; ++kc) {
    bf16x8 a = load_frag(P + (size_t)arow * RANK + kc * 32 + q * 8);
#pragma unroll
    for (int nt = 0; nt < 4; ++nt) {
      bf16x8 b = load_frag(packWx + ((size_t)(kc * 256 + blockIdx.x * 4 + nt) * 64 + lane) * 8);
      acc[nt] = __builtin_amdgcn_mfma_f32_16x16x32_bf16(a, b, acc[nt], 0, 0, 0);
    }
  }
#pragma unroll
  for (int nt = 0; nt < 4; ++nt) {
    int j = n0 + nt * 16 + ln;
    int e = j & (HID - 1);
    float cj = corr[j], bj = bias[j];
#pragma unroll
    for (int r = 0; r < 4; ++r) {
      int m = m0 + w * 16 + q * 4 + r;
      float v = acc[nt][r] + x[(size_t)m * DIM + e] * cj + bj;
      gx[(size_t)m * FOURH + j] = f2bf(v);
    }
  }
}

// Persistent recurrent kernel: 256 blocks (1/CU), one grid barrier per step.
// Distributed barrier: block b release-stores step number into its own padded
// slot (no RMW contention); thread tid of every block spins on slots[tid]
// (thread i watches block i); __syncthreads() is the AND-reduction.
__global__ __launch_bounds__(256, 1) void k_rec(
    const unsigned short* __restrict__ pAh,
    const unsigned short* __restrict__ gx,
    const float* __restrict__ c0,
    unsigned short* __restrict__ hbuf,
    float* __restrict__ out,
    unsigned int* __restrict__ slots) {
  const int tid = threadIdx.x;
  const int w = tid >> 6, lane = tid & 63;
  const int q = lane >> 4, ln = lane & 15;
  const int blk = blockIdx.x;
  const int cg = blk & 63, bg = blk >> 6;

  bf16x8 bfr[32];
#pragma unroll
  for (int kc = 0; kc < 32; ++kc)
    bfr[kc] = load_frag(pAh + ((size_t)((cg * 4 + w) * 32 + kc) * 64 + lane) * 8);

  const int rb = tid >> 4, ee = tid & 15;
  const int brow = bg * 16 + rb;
  const int e = cg * 16 + ee;
  float c = c0[brow * HID + e];

  __shared__ float pre[4][16][16];

  const int arow = bg * 16 + ln;

  unsigned int* myslot  = slots + (size_t)tid * 16;  // watch block `tid`
  unsigned int* arrslot = slots + (size_t)blk * 16;  // my arrival slot

  // Prefetch gx for t=0
  {
    size_t g0 = (size_t)brow * FOURH;
    float a = bf2f(gx[g0 + e]);
    float b = bf2f(gx[g0 + HID + e]);
    float cc = bf2f(gx[g0 + 2 * HID + e]);
    float d = bf2f(gx[g0 + 3 * HID + e]);
    pre[0][0][0] = 0.f; // no-op touch to keep structure; overwritten below
    (void)a; (void)b; (void)cc; (void)d;
    // store into running regs
    // (assigned below via variables)
  }
  size_t g0 = (size_t)brow * FOURH;
  float gx0 = bf2f(gx[g0 + e]);
  float gx1 = bf2f(gx[g0 + HID + e]);
  float gx2 = bf2f(gx[g0 + 2 * HID + e]);
  float gx3 = bf2f(gx[g0 + 3 * HID + e]);

  for (int t = 0; t < T_STEPS; ++t) {
    const int cur = t & 1;
    const unsigned short* hrow = hbuf + cur * (BATCH * HID) + arow * HID + q * 8;
    f32x4 a0 = {}, a1 = {}, a2 = {}, a3 = {};
#pragma unroll
    for (int kc = 0; kc < 32; kc += 4) {
      a0 = __builtin_amdgcn_mfma_f32_16x16x32_bf16(load_frag(hrow + (kc    ) * 32), bfr[kc    ], a0, 0, 0, 0);
      a1 = __builtin_amdgcn_mfma_f32_16x16x32_bf16(load_frag(hrow + (kc + 1) * 32), bfr[kc + 1], a1, 0, 0, 0);
      a2 = __builtin_amdgcn_mfma_f32_16x16x32_bf16(load_frag(hrow + (kc + 2) * 32), bfr[kc + 2], a2, 0, 0, 0);
      a3 = __builtin_amdgcn_mfma_f32_16x16x32_bf16(load_frag(hrow + (kc + 3) * 32), bfr[kc + 3], a3, 0, 0, 0);
    }
#pragma unroll
    for (int r = 0; r < 4; ++r)
      pre[w][q * 4 + r][ln] = (a0[r] + a1[r]) + (a2[r] + a3[r]);
    __syncthreads();

    float p0 = pre[0][rb][ee] + gx0;
    float p1 = pre[1][rb][ee] + gx1;
    float p2 = pre[2][rb][ee] + gx2;
    float p3 = pre[3][rb][ee] + gx3;

    // Prefetch gx for t+1 — independent of the barrier; latency hides in the spin.
    const int tn = (t + 1 < T_STEPS) ? (t + 1) : t;
    const size_t gn = ((size_t)tn * BATCH + brow) * FOURH;
    unsigned short n0 = gx[gn + e];
    unsigned short n1 = gx[gn + HID + e];
    unsigned short n2 = gx[gn + 2 * HID + e];
    unsigned short n3 = gx[gn + 3 * HID + e];

    float gi = 1.f / (1.f + __expf(-p0));
    float gf = 1.f / (1.f + __expf(-p1));
    float go = 1.f / (1.f + __expf(-p2));
    float gn_ = tanhf(p3);
    c = gf * c + gi * gn_;
    float hn = go * tanhf(c);
    out[((size_t)t * BATCH + brow) * HID + e] = hn;
    hbuf[(cur ^ 1) * (BATCH * HID) + brow * HID + e] = f2bf(hn);
    if (t == T_STEPS - 1) {
      out[(size_t)T_STEPS * BATCH * HID + brow * HID + e] = hn;              // h_f
      out[(size_t)T_STEPS * BATCH * HID + BATCH * HID + brow * HID + e] = c; // c_f
    }
    __syncthreads();  // all threads' stores issued & drained (vmcnt0 at barrier)
    if (tid == 0) {
      __threadfence();  // release: flush dirty L2 -> coherence point
      __hip_atomic_store(arrslot, (unsigned int)(t + 1), __ATOMIC_RELAXED,
                         __HIP_MEMORY_SCOPE_AGENT);
    }
    while (__hip_atomic_load(myslot, __ATOMIC_RELAXED, __HIP_MEMORY_SCOPE_AGENT) <
           (unsigned int)(t + 1))
      __builtin_amdgcn_s_sleep(1);
    __syncthreads();  // all 256 slots observed >= t+1 by this block
    if (tid == 0) __threadfence();  // acquire: invalidate L2 so h reads are fresh
    __syncthreads();

    gx0 = bf2f(n0); gx1 = bf2f(n1); gx2 = bf2f(n2); gx3 = bf2f(n3);
  }
}

extern "C" void kernel_launch(void* const* d_in, const int* in_sizes, int n_in,
                              void* d_out, int out_size, void* d_ws, size_t ws_size,
                              hipStream_t stream) {
  const float* x     = (const float*)d_in[0];
  const float* h0    = (const float*)d_in[1];
  const float* c0    = (const float*)d_in[2];
  const float* u_x   = (const float*)d_in[3];
  const float* u_h   = (const float*)d_in[4];
  const float* w_x   = (const float*)d_in[5];
  const float* w_h   = (const float*)d_in[6];
  const float* b_x   = (const float*)d_in[7];
  const float* b_h   = (const float*)d_in[8];
  const float* dia_x = (const float*)d_in[9];
  const float* dia_h = (const float*)d_in[10];
  float* out = (float*)d_out;
  (void)in_sizes; (void)n_in; (void)out_size; (void)ws_size;

  char* base = (char*)d_ws;
  size_t off = 0;
  auto alloc = [&](size_t bytes) -> void* {
    void* p = base + off;
    off = (off + bytes + 255) & ~(size_t)255;
    return p;
  };
  unsigned short* pUx  = (unsigned short*)alloc((size_t)32 * 16 * 64 * 8 * 2);
  unsigned short* pUhT = (unsigned short*)alloc((size_t)8 * 64 * 64 * 8 * 2);
  unsigned short* pWx  = (unsigned short*)alloc((size_t)8 * 256 * 64 * 8 * 2);
  float* corr = (float*)alloc((size_t)FOURH * 4);
  float* bias = (float*)alloc((size_t)FOURH * 4);
  unsigned short* hbuf = (unsigned short*)alloc((size_t)2 * BATCH * HID * 2);
  unsigned int* slots  = (unsigned int*)alloc((size_t)256 * 16 * 4);  // 64B/slot
  unsigned short* P    = (unsigned short*)alloc((size_t)M1 * RANK * 2);
  unsigned short* AhT  = (unsigned short*)alloc((size_t)FOURH * HID * 2);
  unsigned short* pAh  = (unsigned short*)alloc((size_t)64 * 4 * 32 * 64 * 8 * 2);
  unsigned short* gx   = (unsigned short*)alloc((size_t)M1 * FOURH * 2);

  // B-operand packs (one-time, reused by GEMMs / recurrence)
  k_pack<<<128, 256, 0, stream>>>(u_x, pUx, 16, RANK, 0);   // G1 B: u_x [1024 x 256]
  k_pack<<<128, 256, 0, stream>>>(u_h, pUhT, 64, RANK, 1);  // G3 B: u_hT [256 x 1024]
  k_pack<<<512, 256, 0, stream>>>(w_x, pWx, 256, RANK, 1);  // G2 B: w_xT [256 x 4096]
  k_coef<<<1024, 256, 0, stream>>>(u_x, w_x, dia_x, b_x, b_h, corr, bias);
  k_init<<<256, 256, 0, stream>>>(h0, hbuf, slots);
  // G1: P[16384 x 256] = X @ u_x
  k_gemm_a32<<<dim3(4, 256), 256, 0, stream>>>(x, DIM, pUx, 16, 32, P, RANK, nullptr);
  // G3: AhT[4096 x 1024] = w_h @ u_hT, diagonal overridden with dia_h
  k_gemm_a32<<<dim3(16, 64), 256, 0, stream>>>(w_h, RANK, pUhT, 64, 8, AhT, HID, dia_h);
  k_packAh<<<2048, 256, 0, stream>>>(AhT, pAh);
  // G2: gx = P @ w_xT + x*corr + bias  (bf16)
  k_gemm2<<<dim3(64, 256), 256, 0, stream>>>(P, pWx, x, corr, bias, gx);
  // Persistent recurrence
  k_rec<<<256, 256, 0, stream>>>(pAh, gx, c0, hbuf, out, slots);
}

// Round 3
// 1998.535 us; speedup vs baseline: 3.0946x; 2.4056x over previous
//
#include <hip/hip_runtime.h>
#include <stdint.h>

#define T_STEPS 256
#define BATCH 64
#define DIM 1024
#define HID 1024
#define RANK 256
#define FOURH 4096
#define M1 (T_STEPS * BATCH) // 16384

typedef __bf16 bf16_t;
typedef bf16_t bf16x8 __attribute__((ext_vector_type(8)));
typedef float f32x4 __attribute__((ext_vector_type(4)));

union frag_cast { uint4 u; bf16x8 v; };

__device__ __forceinline__ bf16x8 load_frag(const unsigned short* p) {
  frag_cast c; c.u = *reinterpret_cast<const uint4*>(p); return c.v;
}
__device__ __forceinline__ unsigned short f2bf(float f) {
  union { float f; uint32_t u; } v; v.f = f;
  uint32_t u = v.u;
  return (unsigned short)((u + 0x7fffu + ((u >> 16) & 1u)) >> 16);
}
__device__ __forceinline__ float bf2f(unsigned short h) {
  union { uint32_t u; float f; } v; v.u = ((uint32_t)h) << 16; return v.f;
}

// Pack a [K x N] logical B matrix (f32 source) into MFMA B-fragment layout:
// frag (kc, nt): lane l slot s holds B[kc*32 + (l>>4)*8 + s][nt*16 + (l&15)].
__global__ void k_pack(const float* __restrict__ src, unsigned short* __restrict__ dst,
                       int NT, int ld, int transposed) {
  int id = blockIdx.x * blockDim.x + threadIdx.x;
  int lane = id & 63;
  int fi = id >> 6; // kc*NT + nt
  int nt = fi % NT, kc = fi / NT;
  int k0 = kc * 32 + ((lane >> 4) * 8);
  int n  = nt * 16 + (lane & 15);
  unsigned short vals[8];
  if (transposed) {
    const float* p = src + (size_t)n * ld + k0;
#pragma unroll
    for (int s = 0; s < 8; ++s) vals[s] = f2bf(p[s]);
  } else {
#pragma unroll
    for (int s = 0; s < 8; ++s) vals[s] = f2bf(src[(size_t)(k0 + s) * ld + n]);
  }
  union { unsigned short u16[8]; uint4 u; } o;
#pragma unroll
  for (int s = 0; s < 8; ++s) o.u16[s] = vals[s];
  *reinterpret_cast<uint4*>(dst + (size_t)id * 8) = o.u;
}

// corr_x[j] = dia_x[j%H] - dot(u_x[j%H,:], w_x[j,:]);  bias[j] = b_x[j]+b_h[j]
__global__ void k_coef(const float* __restrict__ u_x, const float* __restrict__ w_x,
                       const float* __restrict__ dia_x,
                       const float* __restrict__ b_x, const float* __restrict__ b_h,
                       float* __restrict__ corr, float* __restrict__ bias) {
  int wv = threadIdx.x >> 6, lane = threadIdx.x & 63;
  int j = blockIdx.x * 4 + wv;
  int e = j & (HID - 1);
  const float* up = u_x + (size_t)e * RANK + lane * 4;
  const float* wp = w_x + (size_t)j * RANK + lane * 4;
  float s = up[0] * wp[0] + up[1] * wp[1] + up[2] * wp[2] + up[3] * wp[3];
#pragma unroll
  for (int off = 32; off > 0; off >>= 1) s += __shfl_xor(s, off, 64);
  if (lane == 0) {
    corr[j] = dia_x[e] - s;
    bias[j] = b_x[j] + b_h[j];
  }
}

__global__ void k_init(const float* __restrict__ h0, unsigned short* __restrict__ hbuf,
                       unsigned int* __restrict__ slots) {
  int i = blockIdx.x * blockDim.x + threadIdx.x;
  if (i < 256 * 16) slots[i] = 0u;  // 256 padded barrier slots (64B each)
  hbuf[i] = f2bf(h0[i]); // exactly BATCH*HID threads
}

// C[M x 64*gridDim.x] = A_f32[M x 32*KC] @ packB, store bf16.
// dia != null: C is AhT [j][d]; override C[j][d] = dia[d] when d == j % HID.
__global__ void k_gemm_a32(const float* __restrict__ A, int lda,
                           const unsigned short* __restrict__ packB, int NTtot,
                           int KC, unsigned short* __restrict__ C, int ldc,
                           const float* __restrict__ dia) {
  int w = threadIdx.x >> 6, lane = threadIdx.x & 63;
  int q = lane >> 4, ln = lane & 15;
  int m0 = blockIdx.y * 64, n0 = blockIdx.x * 64;
  int arow = m0 + w * 16 + ln;
  f32x4 acc[4] = {};
  for (int kc = 0; kc < KC; ++kc) {
    const float* ap = A + (size_t)arow * lda + kc * 32 + q * 8;
    float4 x0 = *reinterpret_cast<const float4*>(ap);
    float4 x1 = *reinterpret_cast<const float4*>(ap + 4);
    bf16x8 a;
    a[0] = (bf16_t)x0.x; a[1] = (bf16_t)x0.y; a[2] = (bf16_t)x0.z; a[3] = (bf16_t)x0.w;
    a[4] = (bf16_t)x1.x; a[5] = (bf16_t)x1.y; a[6] = (bf16_t)x1.z; a[7] = (bf16_t)x1.w;
#pragma unroll
    for (int nt = 0; nt < 4; ++nt) {
      bf16x8 b = load_frag(packB + ((size_t)(kc * NTtot + blockIdx.x * 4 + nt) * 64 + lane) * 8);
      acc[nt] = __builtin_amdgcn_mfma_f32_16x16x32_bf16(a, b, acc[nt], 0, 0, 0);
    }
  }
#pragma unroll
  for (int nt = 0; nt < 4; ++nt) {
    int ccol = n0 + nt * 16 + ln;
#pragma unroll
    for (int r = 0; r < 4; ++r) {
      int crow = m0 + w * 16 + q * 4 + r;
      float v = acc[nt][r];
      if (dia != nullptr && ccol == (crow & (HID - 1))) v = dia[ccol];
      C[(size_t)crow * ldc + ccol] = f2bf(v);
    }
  }
}

// Repack AhT [j][d] (bf16) into per-(cg,gate,kc) B-fragment layout for k_rec.
__global__ void k_packAh(const unsigned short* __restrict__ AhT, unsigned short* __restrict__ dst) {
  int id = blockIdx.x * blockDim.x + threadIdx.x;
  int lane = id & 63;
  int fi = id >> 6;        // (cg*4+g)*32 + kc
  int kc = fi & 31;
  int g  = (fi >> 5) & 3;
  int cg = fi >> 7;
  int j  = g * HID + cg * 16 + (lane & 15);
  int d0 = kc * 32 + ((lane >> 4) * 8);
  uint4 v = *reinterpret_cast<const uint4*>(AhT + (size_t)j * HID + d0);
  *reinterpret_cast<uint4*>(dst + (size_t)id * 8) = v;
}

// gx[m][j] = P[m,:] @ w_xT[:,j] + x[m][j%H]*corr[j] + bias[j], store bf16.
__global__ void k_gemm2(const unsigned short* __restrict__ P,
                        const unsigned short* __restrict__ packWx,
                        const float* __restrict__ x,
                        const float* __restrict__ corr, const float* __restrict__ bias,
                        unsigned short* __restrict__ gx) {
  int w = threadIdx.x >> 6, lane = threadIdx.x & 63;
  int q = lane >> 4, ln = lane & 15;
  int m0 = blockIdx.y * 64, n0 = blockIdx.x * 64;
  int arow = m0 + w * 16 + ln;
  f32x4 acc[4] = {};
#pragma unroll
  for (int kc = 0; kc < 8; ++kc) {
    bf16x8 a = load_frag(P + (size_t)arow * RANK + kc * 32 + q * 8);
#pragma unroll
    for (int nt = 0; nt < 4; ++nt) {
      bf16x8 b = load_frag(packWx + ((size_t)(kc * 256 + blockIdx.x * 4 + nt) * 64 + lane) * 8);
      acc[nt] = __builtin_amdgcn_mfma_f32_16x16x32_bf16(a, b, acc[nt], 0, 0, 0);
    }
  }
#pragma unroll
  for (int nt = 0; nt < 4; ++nt) {
    int j = n0 + nt * 16 + ln;
    int e = j & (HID - 1);
    float cj = corr[j], bj = bias[j];
#pragma unroll
    for (int r = 0; r < 4; ++r) {
      int m = m0 + w * 16 + q * 4 + r;
      float v = acc[nt][r] + x[(size_t)m * DIM + e] * cj + bj;
      gx[(size_t)m * FOURH + j] = f2bf(v);
    }
  }
}

// Persistent recurrent kernel. NO threadfence in the loop:
//  - h is exchanged via agent-scope relaxed atomics (sc0 sc1: bypass L2, coherent
//    at L3), so no buffer_inv is needed and pAh/gx stay warm in per-XCD L2.
//  - release ordering: __syncthreads() drains each wave's vmcnt before s_barrier,
//    so all h atomic stores are at L3 before tid0 publishes the barrier slot.
// h(t) is staged once per block into LDS (coalesced 8B atomic loads), then all
// 4 gate-waves read their A-fragments via ds_read_b128 (rows padded +8 shorts).
__global__ __launch_bounds__(256, 1) void k_rec(
    const unsigned short* __restrict__ pAh,
    const unsigned short* __restrict__ gx,
    const float* __restrict__ c0,
    unsigned short* __restrict__ hbuf,
    float* __restrict__ out,
    unsigned int* __restrict__ slots) {
  const int tid = threadIdx.x;
  const int w = tid >> 6, lane = tid & 63;
  const int q = lane >> 4, ln = lane & 15;
  const int blk = blockIdx.x;
  const int cg = blk & 63, bg = blk >> 6;

  const int rb = tid >> 4, ee = tid & 15;
  const int brow = bg * 16 + rb;
  const int e = cg * 16 + ee;
  float c = c0[brow * HID + e];

  __shared__ unsigned short hstage[16][1032];  // 16 h-rows, +8 pad vs banks
  __shared__ float pre[4][16][16];
  __shared__ unsigned short tile[16][16];

  unsigned int* myslot  = slots + (size_t)tid * 16;  // watch block `tid`
  unsigned int* arrslot = slots + (size_t)blk * 16;  // my arrival slot

  // gx prefetch for t=0 (normal cached loads)
  size_t g0 = (size_t)brow * FOURH;
  float gx0 = bf2f(gx[g0 + e]);
  float gx1 = bf2f(gx[g0 + HID + e]);
  float gx2 = bf2f(gx[g0 + 2 * HID + e]);
  float gx3 = bf2f(gx[g0 + 3 * HID + e]);

  for (int t = 0; t < T_STEPS; ++t) {
    const int cur = t & 1;

    // B fragments: identical every step; L2-resident (per-XCD slice ~1 MB).
    bf16x8 bfr[32];
#pragma unroll
    for (int kc = 0; kc < 32; ++kc)
      bfr[kc] = load_frag(pAh + ((size_t)((cg * 4 + w) * 32 + kc) * 64 + lane) * 8);

    // Stage h(t): 16 rows x 1024 cols bf16 = 32 KB, as 4096 u64 atomic loads
    // (bypass L2 -> L3 coherence point). Thread tid takes u64-column tid.
    const unsigned short* hb = hbuf + cur * (BATCH * HID);
#pragma unroll
    for (int it = 0; it < 16; ++it) {
      unsigned long long v = __hip_atomic_load(
          (const unsigned long long*)(hb + (size_t)(bg * 16 + it) * HID + tid * 4),
          __ATOMIC_RELAXED, __HIP_MEMORY_SCOPE_AGENT);
      *reinterpret_cast<unsigned long long*>(&hstage[it][tid * 4]) = v;
    }
    __syncthreads();

    f32x4 a0 = {}, a1 = {}, a2 = {}, a3 = {};
#pragma unroll
    for (int kc = 0; kc < 32; kc += 4) {
      a0 = __builtin_amdgcn_mfma_f32_16x16x32_bf16(load_frag(&hstage[ln][(kc    ) * 32 + q * 8]), bfr[kc    ], a0, 0, 0, 0);
      a1 = __builtin_amdgcn_mfma_f32_16x16x32_bf16(load_frag(&hstage[ln][(kc + 1) * 32 + q * 8]), bfr[kc + 1], a1, 0, 0, 0);
      a2 = __builtin_amdgcn_mfma_f32_16x16x32_bf16(load_frag(&hstage[ln][(kc + 2) * 32 + q * 8]), bfr[kc + 2], a2, 0, 0, 0);
      a3 = __builtin_amdgcn_mfma_f32_16x16x32_bf16(load_frag(&hstage[ln][(kc + 3) * 32 + q * 8]), bfr[kc + 3], a3, 0, 0, 0);
    }
#pragma unroll
    for (int r = 0; r < 4; ++r)
      pre[w][q * 4 + r][ln] = (a0[r] + a1[r]) + (a2[r] + a3[r]);
    __syncthreads();

    float p0 = pre[0][rb][ee] + gx0;
    float p1 = pre[1][rb][ee] + gx1;
    float p2 = pre[2][rb][ee] + gx2;
    float p3 = pre[3][rb][ee] + gx3;

    // Prefetch gx(t+1) — latency hides under the barrier spin.
    const int tn = (t + 1 < T_STEPS) ? (t + 1) : t;
    const size_t gn = ((size_t)tn * BATCH + brow) * FOURH;
    unsigned short n0 = gx[gn + e];
    unsigned short n1 = gx[gn + HID + e];
    unsigned short n2 = gx[gn + 2 * HID + e];
    unsigned short n3 = gx[gn + 3 * HID + e];

    float gi = 1.f / (1.f + __expf(-p0));
    float gf = 1.f / (1.f + __expf(-p1));
    float go = 1.f / (1.f + __expf(-p2));
    float gn_ = tanhf(p3);
    c = gf * c + gi * gn_;
    float hn = go * tanhf(c);
    out[((size_t)t * BATCH + brow) * HID + e] = hn;
    tile[rb][ee] = f2bf(hn);
    if (t == T_STEPS - 1) {
      out[(size_t)T_STEPS * BATCH * HID + brow * HID + e] = hn;              // h_f
      out[(size_t)T_STEPS * BATCH * HID + BATCH * HID + brow * HID + e] = c; // c_f
    }
    __syncthreads();  // tile[] complete

    // Publish h(t+1): 64 u64 agent atomic stores (write-through to L3).
    if (tid < 64) {
      int r2 = tid >> 2, gsel = tid & 3;
      unsigned long long v =
          *reinterpret_cast<const unsigned long long*>(&tile[r2][gsel * 4]);
      __hip_atomic_store(
          (unsigned long long*)(hbuf + (size_t)(cur ^ 1) * (BATCH * HID) +
                                (size_t)(bg * 16 + r2) * HID + cg * 16 + gsel * 4),
          v, __ATOMIC_RELAXED, __HIP_MEMORY_SCOPE_AGENT);
    }
    __syncthreads();  // vmcnt(0) drained per wave -> h stores are at L3
    if (tid == 0)
      __hip_atomic_store(arrslot, (unsigned int)(t + 1), __ATOMIC_RELAXED,
                         __HIP_MEMORY_SCOPE_AGENT);
    while (__hip_atomic_load(myslot, __ATOMIC_RELAXED, __HIP_MEMORY_SCOPE_AGENT) <
           (unsigned int)(t + 1))
      __builtin_amdgcn_s_sleep(1);
    __syncthreads();  // all 256 slots observed >= t+1 by this block

    gx0 = bf2f(n0); gx1 = bf2f(n1); gx2 = bf2f(n2); gx3 = bf2f(n3);
  }
}

extern "C" void kernel_launch(void* const* d_in, const int* in_sizes, int n_in,
                              void* d_out, int out_size, void* d_ws, size_t ws_size,
                              hipStream_t stream) {
  const float* x     = (const float*)d_in[0];
  const float* h0    = (const float*)d_in[1];
  const float* c0    = (const float*)d_in[2];
  const float* u_x   = (const float*)d_in[3];
  const float* u_h   = (const float*)d_in[4];
  const float* w_x   = (const float*)d_in[5];
  const float* w_h   = (const float*)d_in[6];
  const float* b_x   = (const float*)d_in[7];
  const float* b_h   = (const float*)d_in[8];
  const float* dia_x = (const float*)d_in[9];
  const float* dia_h = (const float*)d_in[10];
  float* out = (float*)d_out;
  (void)in_sizes; (void)n_in; (void)out_size; (void)ws_size;

  char* base = (char*)d_ws;
  size_t off = 0;
  auto alloc = [&](size_t bytes) -> void* {
    void* p = base + off;
    off = (off + bytes + 255) & ~(size_t)255;
    return p;
  };
  unsigned short* pUx  = (unsigned short*)alloc((size_t)32 * 16 * 64 * 8 * 2);
  unsigned short* pUhT = (unsigned short*)alloc((size_t)8 * 64 * 64 * 8 * 2);
  unsigned short* pWx  = (unsigned short*)alloc((size_t)8 * 256 * 64 * 8 * 2);
  float* corr = (float*)alloc((size_t)FOURH * 4);
  float* bias = (float*)alloc((size_t)FOURH * 4);
  unsigned short* hbuf = (unsigned short*)alloc((size_t)2 * BATCH * HID * 2);
  unsigned int* slots  = (unsigned int*)alloc((size_t)256 * 16 * 4);  // 64B/slot
  unsigned short* P    = (unsigned short*)alloc((size_t)M1 * RANK * 2);
  unsigned short* AhT  = (unsigned short*)alloc((size_t)FOURH * HID * 2);
  unsigned short* pAh  = (unsigned short*)alloc((size_t)64 * 4 * 32 * 64 * 8 * 2);
  unsigned short* gx   = (unsigned short*)alloc((size_t)M1 * FOURH * 2);

  // B-operand packs (one-time, reused by GEMMs / recurrence)
  k_pack<<<128, 256, 0, stream>>>(u_x, pUx, 16, RANK, 0);   // G1 B: u_x [1024 x 256]
  k_pack<<<128, 256, 0, stream>>>(u_h, pUhT, 64, RANK, 1);  // G3 B: u_hT [256 x 1024]
  k_pack<<<512, 256, 0, stream>>>(w_x, pWx, 256, RANK, 1);  // G2 B: w_xT [256 x 4096]
  k_coef<<<1024, 256, 0, stream>>>(u_x, w_x, dia_x, b_x, b_h, corr, bias);
  k_init<<<256, 256, 0, stream>>>(h0, hbuf, slots);
  // G1: P[16384 x 256] = X @ u_x
  k_gemm_a32<<<dim3(4, 256), 256, 0, stream>>>(x, DIM, pUx, 16, 32, P, RANK, nullptr);
  // G3: AhT[4096 x 1024] = w_h @ u_hT, diagonal overridden with dia_h
  k_gemm_a32<<<dim3(16, 64), 256, 0, stream>>>(w_h, RANK, pUhT, 64, 8, AhT, HID, dia_h);
  k_packAh<<<2048, 256, 0, stream>>>(AhT, pAh);
  // G2: gx = P @ w_xT + x*corr + bias  (bf16)
  k_gemm2<<<dim3(64, 256), 256, 0, stream>>>(P, pWx, x, corr, bias, gx);
  // Persistent recurrence
  k_rec<<<256, 256, 0, stream>>>(pAh, gx, c0, hbuf, out, slots);
}